// Round 11
// baseline (198.538 us; speedup 1.0000x reference)
//
#include <hip/hip_runtime.h>
#include <math.h>
#include <stdint.h>

// ChebConv GNN: N=50000, E=800000, F=H=64, C=10.
//   degI[i] = out-degree of i ; dis = rsqrt(degI) (0 if 0)
//   h  = relu(x @ W1 + b1)                       (stored bf16)
//   p0 = h @ W20 + b2                            (stored bf16)
//   g' = bf16( dis[row] * (h @ W21) )
//   lap[dst] = -dis[dst] * sum_{src in N(dst)} g'[src]    (CSR gather)
//   out = log_softmax( (relu(p0 + lap) + h) @ Wl + bl )
//
// Gather locality: each row's neighbor list is partitioned into src<N/2 and
// src>=N/2 segments (binB two-cursor). All waves sweep the low half first,
// so the active g16 working set (3.2 MB) fits each XCD's 4 MB L2.

#define NBKT 256
#define BCAP 5120
#define CHUNK 2048

__device__ __forceinline__ unsigned short f2bf(float f) {
    uint32_t u; __builtin_memcpy(&u, &f, 4);
    u += 0x7fffu + ((u >> 16) & 1u);          // RNE
    return (unsigned short)(u >> 16);
}
__device__ __forceinline__ float bf2f(unsigned short s) {
    uint32_t u = (uint32_t)s << 16; float f; __builtin_memcpy(&f, &u, 4);
    return f;
}
__device__ __forceinline__ int xcc_id() {
    int x;
    asm("s_getreg_b32 %0, hwreg(HW_REG_XCC_ID)" : "=s"(x));
    return x;
}

// ---------------- Phase A: coarse binning by dst>>8 + src degree ----------------
__global__ __launch_bounds__(256) void binA_kernel(const int* __restrict__ ei,
                                                   int* __restrict__ gcur,
                                                   uint32_t* __restrict__ pairs,
                                                   int* __restrict__ degI8,
                                                   int E, int n) {
    __shared__ uint32_t stage[CHUNK];
    __shared__ int cnt[NBKT], obase[NBKT], goff[NBKT], curs[NBKT];
    __shared__ int wpart[4], stot;
    int t = threadIdx.x, lane = t & 63, wv = t >> 6;
    int e0 = blockIdx.x * CHUNK;
    int* degP = degI8 + (size_t)(xcc_id() & 7) * n;
    int s[8], d[8];
    bool val[8];
#pragma unroll
    for (int j = 0; j < 8; ++j) {
        int e = e0 + j * 256 + t;
        val[j] = e < E;
        s[j] = val[j] ? ei[e] : 0;
        d[j] = val[j] ? ei[E + e] : 0;
    }
    cnt[t] = 0;
    __syncthreads();
#pragma unroll
    for (int j = 0; j < 8; ++j)
        if (val[j]) {
            atomicAdd(&cnt[d[j] >> 8], 1);
            atomicAdd(&degP[s[j]], 1);
        }
    __syncthreads();
    int cv = cnt[t];
    int v = cv;
#pragma unroll
    for (int dd = 1; dd < 64; dd <<= 1) {
        int u = __shfl_up(v, dd);
        if (lane >= dd) v += u;
    }
    if (lane == 63) wpart[wv] = v;
    __syncthreads();
    if (t == 0) {
        int r = 0;
#pragma unroll
        for (int w = 0; w < 4; ++w) { int tmp = wpart[w]; wpart[w] = r; r += tmp; }
        stot = r;
    }
    __syncthreads();
    int eb = wpart[wv] + v - cv;
    obase[t] = eb;
    curs[t] = eb;
    goff[t] = (cv > 0) ? atomicAdd(&gcur[t], cv) : 0;
    __syncthreads();
#pragma unroll
    for (int j = 0; j < 8; ++j)
        if (val[j]) {
            int b = d[j] >> 8;
            int pos = atomicAdd(&curs[b], 1);
            stage[pos] = ((uint32_t)d[j] << 16) | (uint32_t)s[j];  // b:8|ld:8|src:16
        }
    __syncthreads();
    int tot = stot;
    for (int k = t; k < tot; k += 256) {
        uint32_t u = stage[k];
        int b = (int)(u >> 24);
        int slot = goff[b] + (k - obase[b]);
        if (slot < BCAP) pairs[(size_t)b * BCAP + slot] = u;
    }
}

// --- Phase B: per-bucket CSR build, src-half split, + folded dis ---
__global__ __launch_bounds__(256) void binB_kernel(const int* __restrict__ gcur,
                                                   const uint32_t* __restrict__ pairs,
                                                   int* __restrict__ csr,
                                                   int* __restrict__ rowptr,
                                                   int* __restrict__ cntD,
                                                   int* __restrict__ cntLow,
                                                   const int* __restrict__ degI8,
                                                   float* __restrict__ dis,
                                                   int n, int half) {
    __shared__ int hist[NBKT], obase[NBKT], cursL[NBKT], cursH[NBKT];
    __shared__ int wpart[4];
    int t = threadIdx.x, lane = t & 63, wv = t >> 6;
    int b = blockIdx.x;
    {
        int node = b * 256 + t;
        if (node < n) {
            int dsum = 0;
#pragma unroll
            for (int j = 0; j < 8; ++j) dsum += degI8[(size_t)j * n + node];
            dis[node] = (dsum > 0) ? rsqrtf((float)dsum) : 0.0f;
        }
    }
    int nb = gcur[b]; if (nb > BCAP) nb = BCAP;
    hist[t] = 0;
    __syncthreads();
    const uint32_t* bp = pairs + (size_t)b * BCAP;
    for (int k = t; k < nb; k += 256) {
        int ld = (int)((bp[k] >> 16) & 255);
        atomicAdd(&hist[ld], 1);
    }
    __syncthreads();
    int cv = hist[t];
    int v = cv;
#pragma unroll
    for (int dd = 1; dd < 64; dd <<= 1) {
        int u = __shfl_up(v, dd);
        if (lane >= dd) v += u;
    }
    if (lane == 63) wpart[wv] = v;
    __syncthreads();
    if (t == 0) {
        int r = 0;
#pragma unroll
        for (int w = 0; w < 4; ++w) { int tmp = wpart[w]; wpart[w] = r; r += tmp; }
    }
    __syncthreads();
    int eb = wpart[wv] + v - cv;
    obase[t] = eb;
    cursL[t] = eb;          // low-src cursor (ascending)
    cursH[t] = eb + cv;     // high-src cursor (descending, exclusive)
    int node = b * 256 + t;
    if (node < n) {
        rowptr[node] = b * BCAP + eb;
        cntD[node] = cv;
    }
    __syncthreads();
    for (int k = t; k < nb; k += 256) {
        uint32_t u = bp[k];
        int ld = (int)((u >> 16) & 255);
        int src = (int)(u & 0xffffu);
        int pos;
        if (src < half) pos = atomicAdd(&cursL[ld], 1);
        else            pos = atomicSub(&cursH[ld], 1) - 1;
        csr[(size_t)b * BCAP + pos] = src;
    }
    __syncthreads();
    if (node < n) cntLow[node] = cursL[t] - obase[t];
}

// ---- triple GEMM: h16=relu(x@W1+b1); p16=h@W20+b2; g16=bf16(dis*(h@W21)) ----
__global__ __launch_bounds__(256) void gemm3_kernel(const float* __restrict__ x,
                                                    const float* __restrict__ W1,
                                                    const float* __restrict__ b1,
                                                    const float* __restrict__ W20,
                                                    const float* __restrict__ W21,
                                                    const float* __restrict__ b2,
                                                    const float* __restrict__ dis,
                                                    unsigned short* __restrict__ h16,
                                                    unsigned short* __restrict__ p16,
                                                    unsigned short* __restrict__ g16,
                                                    int n) {
    __shared__ __align__(16) float sA[64][68];
    __shared__ __align__(16) float sW1[64][64];
    __shared__ __align__(16) float sW20[64][64];
    __shared__ __align__(16) float sW21[64][64];
    int t = threadIdx.x;
    for (int i = t; i < 4096; i += 256) {
        sW1[i >> 6][i & 63] = W1[i];
        sW20[i >> 6][i & 63] = W20[i];
        sW21[i >> 6][i & 63] = W21[i];
    }
    int r0 = blockIdx.x * 64;
    {
        int rr0 = t >> 4, k0 = (t & 15) * 4;
        for (int rr = rr0; rr < 64; rr += 16) {
            int grow = r0 + rr;
            float4 v = make_float4(0.f, 0.f, 0.f, 0.f);
            if (grow < n) v = *(const float4*)&x[(size_t)grow * 64 + k0];
            sA[k0][rr] = v.x; sA[k0 + 1][rr] = v.y;
            sA[k0 + 2][rr] = v.z; sA[k0 + 3][rr] = v.w;
        }
    }
    __syncthreads();
    int tr = t >> 4, tc = t & 15;

    float acc[4][4] = {};
    for (int k = 0; k < 64; ++k) {
        float4 a = *(const float4*)&sA[k][tr * 4];
        float4 b = *(const float4*)&sW1[k][tc * 4];
        float av[4] = {a.x, a.y, a.z, a.w};
        float bv[4] = {b.x, b.y, b.z, b.w};
#pragma unroll
        for (int i = 0; i < 4; ++i)
#pragma unroll
            for (int j = 0; j < 4; ++j) acc[i][j] = fmaf(av[i], bv[j], acc[i][j]);
    }
    float4 bv1 = *(const float4*)&b1[tc * 4];
    float hv[4][4];
#pragma unroll
    for (int i = 0; i < 4; ++i) {
        hv[i][0] = fmaxf(acc[i][0] + bv1.x, 0.f);
        hv[i][1] = fmaxf(acc[i][1] + bv1.y, 0.f);
        hv[i][2] = fmaxf(acc[i][2] + bv1.z, 0.f);
        hv[i][3] = fmaxf(acc[i][3] + bv1.w, 0.f);
    }
#pragma unroll
    for (int i = 0; i < 4; ++i) {
        int grow = r0 + tr * 4 + i;
        if (grow < n) {
            ushort4 o;
            o.x = f2bf(hv[i][0]); o.y = f2bf(hv[i][1]);
            o.z = f2bf(hv[i][2]); o.w = f2bf(hv[i][3]);
            *(ushort4*)&h16[(size_t)grow * 64 + tc * 4] = o;
        }
    }
    __syncthreads();
#pragma unroll
    for (int i = 0; i < 4; ++i)
#pragma unroll
        for (int j = 0; j < 4; ++j) sA[tc * 4 + j][tr * 4 + i] = hv[i][j];
    __syncthreads();

    float accP[4][4] = {}, accG[4][4] = {};
    for (int k = 0; k < 64; ++k) {
        float4 a = *(const float4*)&sA[k][tr * 4];
        float4 bp = *(const float4*)&sW20[k][tc * 4];
        float4 bg = *(const float4*)&sW21[k][tc * 4];
        float av[4] = {a.x, a.y, a.z, a.w};
        float bpv[4] = {bp.x, bp.y, bp.z, bp.w};
        float bgv[4] = {bg.x, bg.y, bg.z, bg.w};
#pragma unroll
        for (int i = 0; i < 4; ++i)
#pragma unroll
            for (int j = 0; j < 4; ++j) {
                accP[i][j] = fmaf(av[i], bpv[j], accP[i][j]);
                accG[i][j] = fmaf(av[i], bgv[j], accG[i][j]);
            }
    }
    float4 bv2 = *(const float4*)&b2[tc * 4];
#pragma unroll
    for (int i = 0; i < 4; ++i) {
        int grow = r0 + tr * 4 + i;
        if (grow < n) {
            float dr = dis[grow];
            ushort4 op, og;
            op.x = f2bf(accP[i][0] + bv2.x); op.y = f2bf(accP[i][1] + bv2.y);
            op.z = f2bf(accP[i][2] + bv2.z); op.w = f2bf(accP[i][3] + bv2.w);
            og.x = f2bf(dr * accG[i][0]); og.y = f2bf(dr * accG[i][1]);
            og.z = f2bf(dr * accG[i][2]); og.w = f2bf(dr * accG[i][3]);
            *(ushort4*)&p16[(size_t)grow * 64 + tc * 4] = op;
            *(ushort4*)&g16[(size_t)grow * 64 + tc * 4] = og;
        }
    }
}

// ---- gather + epilogue: 4 rows/block; low-src segment first (L2 phase),
// then high; block-level LDS epilogue for the 64->10 proj + log_softmax ----
#define GATHER_SEG(K0, K1)                                                  \
    {                                                                        \
        int k = (K0);                                                        \
        for (; k + 16 <= (K1); k += 16) {                                    \
            int s0 = csr[rs + k],      s1 = csr[rs + k + 1];                 \
            int s2 = csr[rs + k + 2],  s3 = csr[rs + k + 3];                 \
            int s4 = csr[rs + k + 4],  s5 = csr[rs + k + 5];                 \
            int s6 = csr[rs + k + 6],  s7 = csr[rs + k + 7];                 \
            int s8 = csr[rs + k + 8],  s9 = csr[rs + k + 9];                 \
            int sa = csr[rs + k + 10], sb = csr[rs + k + 11];                \
            int sc = csr[rs + k + 12], sd = csr[rs + k + 13];                \
            int se = csr[rs + k + 14], sf = csr[rs + k + 15];                \
            float v0 = bf2f(g16[(size_t)s0 * 64 + c]);                       \
            float v1 = bf2f(g16[(size_t)s1 * 64 + c]);                       \
            float v2 = bf2f(g16[(size_t)s2 * 64 + c]);                       \
            float v3 = bf2f(g16[(size_t)s3 * 64 + c]);                       \
            float v4 = bf2f(g16[(size_t)s4 * 64 + c]);                       \
            float v5 = bf2f(g16[(size_t)s5 * 64 + c]);                       \
            float v6 = bf2f(g16[(size_t)s6 * 64 + c]);                       \
            float v7 = bf2f(g16[(size_t)s7 * 64 + c]);                       \
            float v8 = bf2f(g16[(size_t)s8 * 64 + c]);                       \
            float v9 = bf2f(g16[(size_t)s9 * 64 + c]);                       \
            float va = bf2f(g16[(size_t)sa * 64 + c]);                       \
            float vb = bf2f(g16[(size_t)sb * 64 + c]);                       \
            float vc = bf2f(g16[(size_t)sc * 64 + c]);                       \
            float vd = bf2f(g16[(size_t)sd * 64 + c]);                       \
            float ve = bf2f(g16[(size_t)se * 64 + c]);                       \
            float vf = bf2f(g16[(size_t)sf * 64 + c]);                       \
            a0 += v0 + v8; a1 += v1 + v9; a2 += v2 + va; a3 += v3 + vb;      \
            a4 += v4 + vc; a5 += v5 + vd; a6 += v6 + ve; a7 += v7 + vf;      \
        }                                                                    \
        for (; k + 4 <= (K1); k += 4) {                                      \
            int s0 = csr[rs + k],     s1 = csr[rs + k + 1];                  \
            int s2 = csr[rs + k + 2], s3 = csr[rs + k + 3];                  \
            a0 += bf2f(g16[(size_t)s0 * 64 + c]);                            \
            a1 += bf2f(g16[(size_t)s1 * 64 + c]);                            \
            a2 += bf2f(g16[(size_t)s2 * 64 + c]);                            \
            a3 += bf2f(g16[(size_t)s3 * 64 + c]);                            \
        }                                                                    \
        for (; k < (K1); ++k) {                                              \
            int s0 = csr[rs + k];                                            \
            a0 += bf2f(g16[(size_t)s0 * 64 + c]);                            \
        }                                                                    \
    }

__global__ __launch_bounds__(256, 8) void gather_out_kernel(
        const int* __restrict__ rowptr, const int* __restrict__ cntD,
        const int* __restrict__ cntLow, const int* __restrict__ csr,
        const float* __restrict__ dis,
        const unsigned short* __restrict__ g16, const unsigned short* __restrict__ p16,
        const unsigned short* __restrict__ h16, const float* __restrict__ Wl,
        const float* __restrict__ bl, float* __restrict__ out, int n) {
    __shared__ __align__(16) float so[4][68];     // h2 rows
    __shared__ __align__(16) float sWlT[10][68];  // Wl transposed
    __shared__ float sout[4][12];
    int t = threadIdx.x;
    // stage Wl transposed: 640 floats
    if (t < 160) {
        float4 w = *(const float4*)&Wl[t * 4];
        int i0 = t * 4;
        sWlT[i0 % 10][i0 / 10] = w.x;
        sWlT[(i0 + 1) % 10][(i0 + 1) / 10] = w.y;
        sWlT[(i0 + 2) % 10][(i0 + 2) / 10] = w.z;
        sWlT[(i0 + 3) % 10][(i0 + 3) / 10] = w.w;
    }
    int c = t & 63;
    int wid = __builtin_amdgcn_readfirstlane(t >> 6);
    int row = blockIdx.x * 4 + wid;
    if (row < n) {
        int m = cntD[row], rs = rowptr[row], mL = cntLow[row];
        float disd = dis[row];
        float a0 = 0.f, a1 = 0.f, a2 = 0.f, a3 = 0.f;
        float a4 = 0.f, a5 = 0.f, a6 = 0.f, a7 = 0.f;
        GATHER_SEG(0, mL);        // low-src half: L2-resident phase
        GATHER_SEG(mL, m);        // high-src half
        float lv = -disd * (((a0 + a1) + (a2 + a3)) + ((a4 + a5) + (a6 + a7)));
        float pv = bf2f(p16[(size_t)row * 64 + c]);
        float hv = bf2f(h16[(size_t)row * 64 + c]);
        so[wid][c] = fmaxf(pv + lv, 0.f) + hv;
    }
    __syncthreads();
    // 40 dot-product jobs: (r, j) for 4 rows x 10 classes
    if (t < 40) {
        int r = t / 10, j = t % 10;
        float acc = bl[j];
#pragma unroll
        for (int k0 = 0; k0 < 64; k0 += 4) {
            float4 a = *(const float4*)&so[r][k0];
            float4 b = *(const float4*)&sWlT[j][k0];
            acc = fmaf(a.x, b.x, acc);
            acc = fmaf(a.y, b.y, acc);
            acc = fmaf(a.z, b.z, acc);
            acc = fmaf(a.w, b.w, acc);
        }
        sout[r][j] = acc;
    }
    __syncthreads();
    // softmax: 16-lane groups, one per row
    if (t < 64) {
        int r = t >> 4, l16 = t & 15;
        float v = (l16 < 10) ? sout[r][l16] : -1e30f;
        float mm = v;
#pragma unroll
        for (int d = 1; d < 16; d <<= 1) mm = fmaxf(mm, __shfl_xor(mm, d, 16));
        float e = (l16 < 10) ? expf(v - mm) : 0.f;
        float ss = e;
#pragma unroll
        for (int d = 1; d < 16; d <<= 1) ss += __shfl_xor(ss, d, 16);
        int grow = blockIdx.x * 4 + r;
        if (grow < n && l16 < 10)
            out[(size_t)grow * 10 + l16] = v - mm - logf(ss);
    }
}

extern "C" void kernel_launch(void* const* d_in, const int* in_sizes, int n_in,
                              void* d_out, int out_size, void* d_ws, size_t ws_size,
                              hipStream_t stream) {
    const float* x   = (const float*)d_in[0];
    const int*   ei  = (const int*)d_in[1];
    const float* W1  = (const float*)d_in[2];
    const float* b1  = (const float*)d_in[3];
    const float* W20 = (const float*)d_in[4];
    const float* W21 = (const float*)d_in[5];
    const float* b2  = (const float*)d_in[6];
    const float* Wl  = (const float*)d_in[7];
    const float* bl  = (const float*)d_in[8];
    float* out = (float*)d_out;

    int n = in_sizes[0] / 64;   // 50000
    int E = in_sizes[1] / 2;    // 800000

    char* ws = (char*)d_ws;
    size_t off = 0;
    auto alloc = [&](size_t bytes) {
        void* p = ws + off;
        off = (off + bytes + 255) & ~(size_t)255;
        return p;
    };
    int*       gcur   = (int*)alloc((size_t)NBKT * 4);
    uint32_t*  pairs  = (uint32_t*)alloc((size_t)NBKT * BCAP * 4);  // 5.2 MB
    int*       csr    = (int*)alloc((size_t)NBKT * BCAP * 4);       // 5.2 MB
    int*       rowptr = (int*)alloc((size_t)n * 4);
    int*       cntD   = (int*)alloc((size_t)n * 4);
    int*       cntLow = (int*)alloc((size_t)n * 4);
    int*       degI8  = (int*)alloc((size_t)n * 8 * 4);
    float*     dis    = (float*)alloc((size_t)n * 4);
    unsigned short* h16 = (unsigned short*)alloc((size_t)n * 64 * 2);
    unsigned short* p16 = (unsigned short*)alloc((size_t)n * 64 * 2);
    unsigned short* g16 = (unsigned short*)alloc((size_t)n * 64 * 2);

    hipMemsetAsync(gcur, 0, (size_t)NBKT * 4, stream);
    hipMemsetAsync(degI8, 0, (size_t)n * 8 * 4, stream);

    int nchunk = (E + CHUNK - 1) / CHUNK;
    binA_kernel<<<nchunk, 256, 0, stream>>>(ei, gcur, pairs, degI8, E, n);
    binB_kernel<<<NBKT, 256, 0, stream>>>(gcur, pairs, csr, rowptr, cntD, cntLow,
                                          degI8, dis, n, n / 2);
    gemm3_kernel<<<(n + 63) / 64, 256, 0, stream>>>(x, W1, b1, W20, W21, b2, dis,
                                                    h16, p16, g16, n);
    gather_out_kernel<<<(n + 3) / 4, 256, 0, stream>>>(rowptr, cntD, cntLow, csr,
                                                       dis, g16, p16, h16, Wl, bl,
                                                       out, n);
}

// Round 12
// 193.986 us; speedup vs baseline: 1.0235x; 1.0235x over previous
//
#include <hip/hip_runtime.h>
#include <math.h>
#include <stdint.h>

// ChebConv GNN: N=50000, E=800000, F=H=64, C=10.
//   degI[i] = out-degree of i ; dis = rsqrt(degI) (0 if 0)
//   h  = relu(x @ W1 + b1)                       (stored bf16)
//   p0 = h @ W20 + b2                            (stored bf16)
//   g' = bf16( dis[row] * (h @ W21) )
//   lap[dst] = -dis[dst] * sum_{src in N(dst)} g'[src]    (CSR gather)
//   out = log_softmax( (relu(p0 + lap) + h) @ Wl + bl )
//
// Gather: paired-feature layout — lane l reads uint32 (2 bf16, pair p=l&31);
// lanes 0-31 handle edge k, lanes 32-63 edge k+1 -> one VMEM inst / 2 edges.

#define NBKT 256
#define BCAP 5120
#define CHUNK 2048

__device__ __forceinline__ unsigned short f2bf(float f) {
    uint32_t u; __builtin_memcpy(&u, &f, 4);
    u += 0x7fffu + ((u >> 16) & 1u);          // RNE
    return (unsigned short)(u >> 16);
}
__device__ __forceinline__ float bf2f(unsigned short s) {
    uint32_t u = (uint32_t)s << 16; float f; __builtin_memcpy(&f, &u, 4);
    return f;
}
__device__ __forceinline__ float lo_of(uint32_t u) {
    uint32_t v = u << 16; float f; __builtin_memcpy(&f, &v, 4); return f;
}
__device__ __forceinline__ float hi_of(uint32_t u) {
    uint32_t v = u & 0xffff0000u; float f; __builtin_memcpy(&f, &v, 4); return f;
}
__device__ __forceinline__ int xcc_id() {
    int x;
    asm("s_getreg_b32 %0, hwreg(HW_REG_XCC_ID)" : "=s"(x));
    return x;
}

// ---------------- Phase A: coarse binning by dst>>8 + src degree ----------------
__global__ __launch_bounds__(256) void binA_kernel(const int* __restrict__ ei,
                                                   int* __restrict__ gcur,
                                                   uint32_t* __restrict__ pairs,
                                                   int* __restrict__ degI8,
                                                   int E, int n) {
    __shared__ uint32_t stage[CHUNK];
    __shared__ int cnt[NBKT], obase[NBKT], goff[NBKT], curs[NBKT];
    __shared__ int wpart[4], stot;
    int t = threadIdx.x, lane = t & 63, wv = t >> 6;
    int e0 = blockIdx.x * CHUNK;
    int* degP = degI8 + (size_t)(xcc_id() & 7) * n;
    int s[8], d[8];
    bool val[8];
#pragma unroll
    for (int j = 0; j < 8; ++j) {
        int e = e0 + j * 256 + t;
        val[j] = e < E;
        s[j] = val[j] ? ei[e] : 0;
        d[j] = val[j] ? ei[E + e] : 0;
    }
    cnt[t] = 0;
    __syncthreads();
#pragma unroll
    for (int j = 0; j < 8; ++j)
        if (val[j]) {
            atomicAdd(&cnt[d[j] >> 8], 1);
            atomicAdd(&degP[s[j]], 1);
        }
    __syncthreads();
    int cv = cnt[t];
    int v = cv;
#pragma unroll
    for (int dd = 1; dd < 64; dd <<= 1) {
        int u = __shfl_up(v, dd);
        if (lane >= dd) v += u;
    }
    if (lane == 63) wpart[wv] = v;
    __syncthreads();
    if (t == 0) {
        int r = 0;
#pragma unroll
        for (int w = 0; w < 4; ++w) { int tmp = wpart[w]; wpart[w] = r; r += tmp; }
        stot = r;
    }
    __syncthreads();
    int eb = wpart[wv] + v - cv;
    obase[t] = eb;
    curs[t] = eb;
    goff[t] = (cv > 0) ? atomicAdd(&gcur[t], cv) : 0;
    __syncthreads();
#pragma unroll
    for (int j = 0; j < 8; ++j)
        if (val[j]) {
            int b = d[j] >> 8;
            int pos = atomicAdd(&curs[b], 1);
            stage[pos] = ((uint32_t)d[j] << 16) | (uint32_t)s[j];  // b:8|ld:8|src:16
        }
    __syncthreads();
    int tot = stot;
    for (int k = t; k < tot; k += 256) {
        uint32_t u = stage[k];
        int b = (int)(u >> 24);
        int slot = goff[b] + (k - obase[b]);
        if (slot < BCAP) pairs[(size_t)b * BCAP + slot] = u;
    }
}

// ------- Phase B: per-bucket CSR build (+ folded dis = rsqrt(sum degI8)) -------
__global__ __launch_bounds__(256) void binB_kernel(const int* __restrict__ gcur,
                                                   const uint32_t* __restrict__ pairs,
                                                   int* __restrict__ csr,
                                                   int* __restrict__ rowptr,
                                                   int* __restrict__ cntD,
                                                   const int* __restrict__ degI8,
                                                   float* __restrict__ dis, int n) {
    __shared__ int hist[NBKT], obase[NBKT], curs[NBKT];
    __shared__ int wpart[4];
    int t = threadIdx.x, lane = t & 63, wv = t >> 6;
    int b = blockIdx.x;
    {
        int node = b * 256 + t;
        if (node < n) {
            int dsum = 0;
#pragma unroll
            for (int j = 0; j < 8; ++j) dsum += degI8[(size_t)j * n + node];
            dis[node] = (dsum > 0) ? rsqrtf((float)dsum) : 0.0f;
        }
    }
    int nb = gcur[b]; if (nb > BCAP) nb = BCAP;
    hist[t] = 0;
    __syncthreads();
    const uint32_t* bp = pairs + (size_t)b * BCAP;
    for (int k = t; k < nb; k += 256) {
        int ld = (int)((bp[k] >> 16) & 255);
        atomicAdd(&hist[ld], 1);
    }
    __syncthreads();
    int cv = hist[t];
    int v = cv;
#pragma unroll
    for (int dd = 1; dd < 64; dd <<= 1) {
        int u = __shfl_up(v, dd);
        if (lane >= dd) v += u;
    }
    if (lane == 63) wpart[wv] = v;
    __syncthreads();
    if (t == 0) {
        int r = 0;
#pragma unroll
        for (int w = 0; w < 4; ++w) { int tmp = wpart[w]; wpart[w] = r; r += tmp; }
    }
    __syncthreads();
    int eb = wpart[wv] + v - cv;
    obase[t] = eb;
    curs[t] = eb;
    int node = b * 256 + t;
    if (node < n) {
        rowptr[node] = b * BCAP + eb;
        cntD[node] = cv;
    }
    __syncthreads();
    for (int k = t; k < nb; k += 256) {
        uint32_t u = bp[k];
        int ld = (int)((u >> 16) & 255);
        int pos = atomicAdd(&curs[ld], 1);
        csr[(size_t)b * BCAP + pos] = (int)(u & 0xffffu);
    }
}

// ---- triple GEMM: h16=relu(x@W1+b1); p16=h@W20+b2; g16=bf16(dis*(h@W21)) ----
__global__ __launch_bounds__(256) void gemm3_kernel(const float* __restrict__ x,
                                                    const float* __restrict__ W1,
                                                    const float* __restrict__ b1,
                                                    const float* __restrict__ W20,
                                                    const float* __restrict__ W21,
                                                    const float* __restrict__ b2,
                                                    const float* __restrict__ dis,
                                                    unsigned short* __restrict__ h16,
                                                    unsigned short* __restrict__ p16,
                                                    unsigned short* __restrict__ g16,
                                                    int n) {
    __shared__ __align__(16) float sA[64][68];
    __shared__ __align__(16) float sW1[64][64];
    __shared__ __align__(16) float sW20[64][64];
    __shared__ __align__(16) float sW21[64][64];
    int t = threadIdx.x;
    for (int i = t; i < 4096; i += 256) {
        sW1[i >> 6][i & 63] = W1[i];
        sW20[i >> 6][i & 63] = W20[i];
        sW21[i >> 6][i & 63] = W21[i];
    }
    int r0 = blockIdx.x * 64;
    {
        int rr0 = t >> 4, k0 = (t & 15) * 4;
        for (int rr = rr0; rr < 64; rr += 16) {
            int grow = r0 + rr;
            float4 v = make_float4(0.f, 0.f, 0.f, 0.f);
            if (grow < n) v = *(const float4*)&x[(size_t)grow * 64 + k0];
            sA[k0][rr] = v.x; sA[k0 + 1][rr] = v.y;
            sA[k0 + 2][rr] = v.z; sA[k0 + 3][rr] = v.w;
        }
    }
    __syncthreads();
    int tr = t >> 4, tc = t & 15;

    float acc[4][4] = {};
    for (int k = 0; k < 64; ++k) {
        float4 a = *(const float4*)&sA[k][tr * 4];
        float4 b = *(const float4*)&sW1[k][tc * 4];
        float av[4] = {a.x, a.y, a.z, a.w};
        float bv[4] = {b.x, b.y, b.z, b.w};
#pragma unroll
        for (int i = 0; i < 4; ++i)
#pragma unroll
            for (int j = 0; j < 4; ++j) acc[i][j] = fmaf(av[i], bv[j], acc[i][j]);
    }
    float4 bv1 = *(const float4*)&b1[tc * 4];
    float hv[4][4];
#pragma unroll
    for (int i = 0; i < 4; ++i) {
        hv[i][0] = fmaxf(acc[i][0] + bv1.x, 0.f);
        hv[i][1] = fmaxf(acc[i][1] + bv1.y, 0.f);
        hv[i][2] = fmaxf(acc[i][2] + bv1.z, 0.f);
        hv[i][3] = fmaxf(acc[i][3] + bv1.w, 0.f);
    }
#pragma unroll
    for (int i = 0; i < 4; ++i) {
        int grow = r0 + tr * 4 + i;
        if (grow < n) {
            ushort4 o;
            o.x = f2bf(hv[i][0]); o.y = f2bf(hv[i][1]);
            o.z = f2bf(hv[i][2]); o.w = f2bf(hv[i][3]);
            *(ushort4*)&h16[(size_t)grow * 64 + tc * 4] = o;
        }
    }
    __syncthreads();
#pragma unroll
    for (int i = 0; i < 4; ++i)
#pragma unroll
        for (int j = 0; j < 4; ++j) sA[tc * 4 + j][tr * 4 + i] = hv[i][j];
    __syncthreads();

    float accP[4][4] = {}, accG[4][4] = {};
    for (int k = 0; k < 64; ++k) {
        float4 a = *(const float4*)&sA[k][tr * 4];
        float4 bp = *(const float4*)&sW20[k][tc * 4];
        float4 bg = *(const float4*)&sW21[k][tc * 4];
        float av[4] = {a.x, a.y, a.z, a.w};
        float bpv[4] = {bp.x, bp.y, bp.z, bp.w};
        float bgv[4] = {bg.x, bg.y, bg.z, bg.w};
#pragma unroll
        for (int i = 0; i < 4; ++i)
#pragma unroll
            for (int j = 0; j < 4; ++j) {
                accP[i][j] = fmaf(av[i], bpv[j], accP[i][j]);
                accG[i][j] = fmaf(av[i], bgv[j], accG[i][j]);
            }
    }
    float4 bv2 = *(const float4*)&b2[tc * 4];
#pragma unroll
    for (int i = 0; i < 4; ++i) {
        int grow = r0 + tr * 4 + i;
        if (grow < n) {
            float dr = dis[grow];
            ushort4 op, og;
            op.x = f2bf(accP[i][0] + bv2.x); op.y = f2bf(accP[i][1] + bv2.y);
            op.z = f2bf(accP[i][2] + bv2.z); op.w = f2bf(accP[i][3] + bv2.w);
            og.x = f2bf(dr * accG[i][0]); og.y = f2bf(dr * accG[i][1]);
            og.z = f2bf(dr * accG[i][2]); og.w = f2bf(dr * accG[i][3]);
            *(ushort4*)&p16[(size_t)grow * 64 + tc * 4] = op;
            *(ushort4*)&g16[(size_t)grow * 64 + tc * 4] = og;
        }
    }
}

// ---- gather + epilogue: paired-feature gather (2 edges / VMEM inst) ----
__global__ __launch_bounds__(256, 8) void gather_out_kernel(
        const int* __restrict__ rowptr, const int* __restrict__ cntD,
        const int* __restrict__ csr, const float* __restrict__ dis,
        const uint32_t* __restrict__ gp, const uint32_t* __restrict__ pp,
        const uint32_t* __restrict__ hp, const float* __restrict__ Wl,
        const float* __restrict__ bl, float* __restrict__ out, int n) {
    __shared__ __align__(16) float so[4][68];     // h2 rows
    __shared__ __align__(16) float sWlT[10][68];  // Wl transposed
    __shared__ float sout[4][12];
    int t = threadIdx.x;
    if (t < 160) {
        float4 w = *(const float4*)&Wl[t * 4];
        int i0 = t * 4;
        sWlT[i0 % 10][i0 / 10] = w.x;
        sWlT[(i0 + 1) % 10][(i0 + 1) / 10] = w.y;
        sWlT[(i0 + 2) % 10][(i0 + 2) / 10] = w.z;
        sWlT[(i0 + 3) % 10][(i0 + 3) / 10] = w.w;
    }
    int p = t & 31;                 // feature-pair index (features 2p, 2p+1)
    int eslot = (t >> 5) & 1;       // which edge of the pair this lane serves
    int wid = __builtin_amdgcn_readfirstlane(t >> 6);
    int row = blockIdx.x * 4 + wid;
    if (row < n) {
        int m = cntD[row], rs = rowptr[row];
        float disd = dis[row];
        float l0 = 0.f, l1 = 0.f, l2 = 0.f, l3 = 0.f;
        float h0 = 0.f, h1 = 0.f, h2a = 0.f, h3 = 0.f;
        int k = 0;
        for (; k + 16 <= m; k += 16) {
            int sA0 = csr[rs + k + 0],  sA1 = csr[rs + k + 1];
            int sA2 = csr[rs + k + 2],  sA3 = csr[rs + k + 3];
            int sA4 = csr[rs + k + 4],  sA5 = csr[rs + k + 5];
            int sA6 = csr[rs + k + 6],  sA7 = csr[rs + k + 7];
            int sA8 = csr[rs + k + 8],  sA9 = csr[rs + k + 9];
            int sAa = csr[rs + k + 10], sAb = csr[rs + k + 11];
            int sAc = csr[rs + k + 12], sAd = csr[rs + k + 13];
            int sAe = csr[rs + k + 14], sAf = csr[rs + k + 15];
            int e0 = eslot ? sA1 : sA0;
            int e1 = eslot ? sA3 : sA2;
            int e2 = eslot ? sA5 : sA4;
            int e3 = eslot ? sA7 : sA6;
            int e4 = eslot ? sA9 : sA8;
            int e5 = eslot ? sAb : sAa;
            int e6 = eslot ? sAd : sAc;
            int e7 = eslot ? sAf : sAe;
            uint32_t u0 = gp[(size_t)e0 * 32 + p];
            uint32_t u1 = gp[(size_t)e1 * 32 + p];
            uint32_t u2 = gp[(size_t)e2 * 32 + p];
            uint32_t u3 = gp[(size_t)e3 * 32 + p];
            uint32_t u4 = gp[(size_t)e4 * 32 + p];
            uint32_t u5 = gp[(size_t)e5 * 32 + p];
            uint32_t u6 = gp[(size_t)e6 * 32 + p];
            uint32_t u7 = gp[(size_t)e7 * 32 + p];
            l0 += lo_of(u0); h0 += hi_of(u0);
            l1 += lo_of(u1); h1 += hi_of(u1);
            l2 += lo_of(u2); h2a += hi_of(u2);
            l3 += lo_of(u3); h3 += hi_of(u3);
            l0 += lo_of(u4); h0 += hi_of(u4);
            l1 += lo_of(u5); h1 += hi_of(u5);
            l2 += lo_of(u6); h2a += hi_of(u6);
            l3 += lo_of(u7); h3 += hi_of(u7);
        }
        for (; k + 2 <= m; k += 2) {
            int s0 = csr[rs + k], s1 = csr[rs + k + 1];
            int e = eslot ? s1 : s0;
            uint32_t u = gp[(size_t)e * 32 + p];
            l0 += lo_of(u); h0 += hi_of(u);
        }
        if (k < m) {
            int s0 = csr[rs + k];
            if (eslot == 0) {
                uint32_t u = gp[(size_t)s0 * 32 + p];
                l0 += lo_of(u); h0 += hi_of(u);
            }
        }
        float alo = (l0 + l1) + (l2 + l3);
        float ahi = (h0 + h1) + (h2a + h3);
        alo += __shfl_xor(alo, 32);
        ahi += __shfl_xor(ahi, 32);
        uint32_t up = pp[(size_t)row * 32 + p];
        uint32_t uh = hp[(size_t)row * 32 + p];
        float h2lo = fmaxf(lo_of(up) - disd * alo, 0.f) + lo_of(uh);
        float h2hi = fmaxf(hi_of(up) - disd * ahi, 0.f) + hi_of(uh);
        if (eslot == 0) {
            so[wid][2 * p] = h2lo;
            so[wid][2 * p + 1] = h2hi;
        }
    }
    __syncthreads();
    // 40 dot-product jobs: (r, j) for 4 rows x 10 classes
    if (t < 40) {
        int r = t / 10, j = t % 10;
        float acc = bl[j];
#pragma unroll
        for (int k0 = 0; k0 < 64; k0 += 4) {
            float4 a = *(const float4*)&so[r][k0];
            float4 b = *(const float4*)&sWlT[j][k0];
            acc = fmaf(a.x, b.x, acc);
            acc = fmaf(a.y, b.y, acc);
            acc = fmaf(a.z, b.z, acc);
            acc = fmaf(a.w, b.w, acc);
        }
        sout[r][j] = acc;
    }
    __syncthreads();
    // softmax: 16-lane groups, one per row
    if (t < 64) {
        int r = t >> 4, l16 = t & 15;
        float v = (l16 < 10) ? sout[r][l16] : -1e30f;
        float mm = v;
#pragma unroll
        for (int d = 1; d < 16; d <<= 1) mm = fmaxf(mm, __shfl_xor(mm, d, 16));
        float e = (l16 < 10) ? expf(v - mm) : 0.f;
        float ss = e;
#pragma unroll
        for (int d = 1; d < 16; d <<= 1) ss += __shfl_xor(ss, d, 16);
        int grow = blockIdx.x * 4 + r;
        if (grow < n && l16 < 10)
            out[(size_t)grow * 10 + l16] = v - mm - logf(ss);
    }
}

extern "C" void kernel_launch(void* const* d_in, const int* in_sizes, int n_in,
                              void* d_out, int out_size, void* d_ws, size_t ws_size,
                              hipStream_t stream) {
    const float* x   = (const float*)d_in[0];
    const int*   ei  = (const int*)d_in[1];
    const float* W1  = (const float*)d_in[2];
    const float* b1  = (const float*)d_in[3];
    const float* W20 = (const float*)d_in[4];
    const float* W21 = (const float*)d_in[5];
    const float* b2  = (const float*)d_in[6];
    const float* Wl  = (const float*)d_in[7];
    const float* bl  = (const float*)d_in[8];
    float* out = (float*)d_out;

    int n = in_sizes[0] / 64;   // 50000
    int E = in_sizes[1] / 2;    // 800000

    char* ws = (char*)d_ws;
    size_t off = 0;
    auto alloc = [&](size_t bytes) {
        void* p = ws + off;
        off = (off + bytes + 255) & ~(size_t)255;
        return p;
    };
    int*       gcur   = (int*)alloc((size_t)NBKT * 4);
    uint32_t*  pairs  = (uint32_t*)alloc((size_t)NBKT * BCAP * 4);  // 5.2 MB
    int*       csr    = (int*)alloc((size_t)NBKT * BCAP * 4);       // 5.2 MB
    int*       rowptr = (int*)alloc((size_t)n * 4);
    int*       cntD   = (int*)alloc((size_t)n * 4);
    int*       degI8  = (int*)alloc((size_t)n * 8 * 4);
    float*     dis    = (float*)alloc((size_t)n * 4);
    unsigned short* h16 = (unsigned short*)alloc((size_t)n * 64 * 2);
    unsigned short* p16 = (unsigned short*)alloc((size_t)n * 64 * 2);
    unsigned short* g16 = (unsigned short*)alloc((size_t)n * 64 * 2);

    hipMemsetAsync(gcur, 0, (size_t)NBKT * 4, stream);
    hipMemsetAsync(degI8, 0, (size_t)n * 8 * 4, stream);

    int nchunk = (E + CHUNK - 1) / CHUNK;
    binA_kernel<<<nchunk, 256, 0, stream>>>(ei, gcur, pairs, degI8, E, n);
    binB_kernel<<<NBKT, 256, 0, stream>>>(gcur, pairs, csr, rowptr, cntD, degI8, dis, n);
    gemm3_kernel<<<(n + 63) / 64, 256, 0, stream>>>(x, W1, b1, W20, W21, b2, dis,
                                                    h16, p16, g16, n);
    gather_out_kernel<<<(n + 3) / 4, 256, 0, stream>>>(rowptr, cntD, csr, dis,
                                                       (const uint32_t*)g16,
                                                       (const uint32_t*)p16,
                                                       (const uint32_t*)h16,
                                                       Wl, bl, out, n);
}

// Round 13
// 187.555 us; speedup vs baseline: 1.0586x; 1.0343x over previous
//
#include <hip/hip_runtime.h>
#include <math.h>
#include <stdint.h>

// ChebConv GNN: N=50000, E=800000, F=H=64, C=10.
//   degS[i] = out-degree of i ; dis = rsqrt(degS) (0 if 0)
//   h  = relu(x @ W1 + b1)                       (stored bf16)
//   p0 = h @ W20 + b2                            (stored bf16)
//   g' = bf16( dis[row] * (h @ W21) )
//   lap[dst] = -dis[dst] * sum_{src in N(dst)} g'[src]    (CSR gather)
//   out = log_softmax( (relu(p0 + lap) + h) @ Wl + bl )
//
// Degree: range x slice LDS histogram (256 blocks, coalesced merge atomics)
// replaces 800k random global atomics in binA (r5-r10 evidence: ~30 us cost).

#define NBKT 256
#define BCAP 5120
#define CHUNK 2048
#define RB 12800   // histogram bins per range (51.2 KB LDS); 4 ranges cover 51200
#define NSLICE 64

__device__ __forceinline__ unsigned short f2bf(float f) {
    uint32_t u; __builtin_memcpy(&u, &f, 4);
    u += 0x7fffu + ((u >> 16) & 1u);          // RNE
    return (unsigned short)(u >> 16);
}
__device__ __forceinline__ float bf2f(unsigned short s) {
    uint32_t u = (uint32_t)s << 16; float f; __builtin_memcpy(&f, &u, 4);
    return f;
}
__device__ __forceinline__ float lo_of(uint32_t u) {
    uint32_t v = u << 16; float f; __builtin_memcpy(&f, &v, 4); return f;
}
__device__ __forceinline__ float hi_of(uint32_t u) {
    uint32_t v = u & 0xffff0000u; float f; __builtin_memcpy(&f, &v, 4); return f;
}

// ---------------- Phase A: coarse binning by dst>>8 (no degree atomics) --------
__global__ __launch_bounds__(256) void binA_kernel(const int* __restrict__ ei,
                                                   int* __restrict__ gcur,
                                                   uint32_t* __restrict__ pairs,
                                                   int E) {
    __shared__ uint32_t stage[CHUNK];
    __shared__ int cnt[NBKT], obase[NBKT], goff[NBKT], curs[NBKT];
    __shared__ int wpart[4], stot;
    int t = threadIdx.x, lane = t & 63, wv = t >> 6;
    int e0 = blockIdx.x * CHUNK;
    int s[8], d[8];
    bool val[8];
#pragma unroll
    for (int j = 0; j < 8; ++j) {
        int e = e0 + j * 256 + t;
        val[j] = e < E;
        s[j] = val[j] ? ei[e] : 0;
        d[j] = val[j] ? ei[E + e] : 0;
    }
    cnt[t] = 0;
    __syncthreads();
#pragma unroll
    for (int j = 0; j < 8; ++j)
        if (val[j]) atomicAdd(&cnt[d[j] >> 8], 1);
    __syncthreads();
    int cv = cnt[t];
    int v = cv;
#pragma unroll
    for (int dd = 1; dd < 64; dd <<= 1) {
        int u = __shfl_up(v, dd);
        if (lane >= dd) v += u;
    }
    if (lane == 63) wpart[wv] = v;
    __syncthreads();
    if (t == 0) {
        int r = 0;
#pragma unroll
        for (int w = 0; w < 4; ++w) { int tmp = wpart[w]; wpart[w] = r; r += tmp; }
        stot = r;
    }
    __syncthreads();
    int eb = wpart[wv] + v - cv;
    obase[t] = eb;
    curs[t] = eb;
    goff[t] = (cv > 0) ? atomicAdd(&gcur[t], cv) : 0;
    __syncthreads();
#pragma unroll
    for (int j = 0; j < 8; ++j)
        if (val[j]) {
            int b = d[j] >> 8;
            int pos = atomicAdd(&curs[b], 1);
            stage[pos] = ((uint32_t)d[j] << 16) | (uint32_t)s[j];  // b:8|ld:8|src:16
        }
    __syncthreads();
    int tot = stot;
    for (int k = t; k < tot; k += 256) {
        uint32_t u = stage[k];
        int b = (int)(u >> 24);
        int slot = goff[b] + (k - obase[b]);
        if (slot < BCAP) pairs[(size_t)b * BCAP + slot] = u;
    }
}

// ------- degree histogram: 4 ranges x 64 slices, coalesced merge atomics -------
__global__ __launch_bounds__(256) void deghist_kernel(const int* __restrict__ ei,
                                                      int* __restrict__ degS,
                                                      int E, int n) {
    __shared__ int bins[RB];
    int t = threadIdx.x;
    int r = blockIdx.x & 3;
    int sl = blockIdx.x >> 2;
    int lo = r * RB;
    for (int i = t; i < RB; i += 256) bins[i] = 0;
    __syncthreads();
    int per = (E + NSLICE - 1) / NSLICE;
    int b0 = sl * per, b1 = b0 + per; if (b1 > E) b1 = E;
    for (int e = b0 + t; e < b1; e += 256) {
        int s = ei[e] - lo;
        if ((unsigned)s < (unsigned)RB) atomicAdd(&bins[s], 1);
    }
    __syncthreads();
    int hi = n - lo; if (hi > RB) hi = RB;
    for (int i = t; i < hi; i += 256) {
        int v = bins[i];
        if (v) atomicAdd(&degS[lo + i], v);   // sequential addrs -> coalesced
    }
}

// ------- Phase B: per-bucket CSR build (+ folded dis = rsqrt(degS)) -------
__global__ __launch_bounds__(256) void binB_kernel(const int* __restrict__ gcur,
                                                   const uint32_t* __restrict__ pairs,
                                                   int* __restrict__ csr,
                                                   int* __restrict__ rowptr,
                                                   int* __restrict__ cntD,
                                                   const int* __restrict__ degS,
                                                   float* __restrict__ dis, int n) {
    __shared__ int hist[NBKT], obase[NBKT], curs[NBKT];
    __shared__ int wpart[4];
    int t = threadIdx.x, lane = t & 63, wv = t >> 6;
    int b = blockIdx.x;
    {
        int node = b * 256 + t;
        if (node < n) {
            int dsum = degS[node];
            dis[node] = (dsum > 0) ? rsqrtf((float)dsum) : 0.0f;
        }
    }
    int nb = gcur[b]; if (nb > BCAP) nb = BCAP;
    hist[t] = 0;
    __syncthreads();
    const uint32_t* bp = pairs + (size_t)b * BCAP;
    for (int k = t; k < nb; k += 256) {
        int ld = (int)((bp[k] >> 16) & 255);
        atomicAdd(&hist[ld], 1);
    }
    __syncthreads();
    int cv = hist[t];
    int v = cv;
#pragma unroll
    for (int dd = 1; dd < 64; dd <<= 1) {
        int u = __shfl_up(v, dd);
        if (lane >= dd) v += u;
    }
    if (lane == 63) wpart[wv] = v;
    __syncthreads();
    if (t == 0) {
        int r = 0;
#pragma unroll
        for (int w = 0; w < 4; ++w) { int tmp = wpart[w]; wpart[w] = r; r += tmp; }
    }
    __syncthreads();
    int eb = wpart[wv] + v - cv;
    obase[t] = eb;
    curs[t] = eb;
    int node = b * 256 + t;
    if (node < n) {
        rowptr[node] = b * BCAP + eb;
        cntD[node] = cv;
    }
    __syncthreads();
    for (int k = t; k < nb; k += 256) {
        uint32_t u = bp[k];
        int ld = (int)((u >> 16) & 255);
        int pos = atomicAdd(&curs[ld], 1);
        csr[(size_t)b * BCAP + pos] = (int)(u & 0xffffu);
    }
}

// ---- triple GEMM: h16=relu(x@W1+b1); p16=h@W20+b2; g16=bf16(dis*(h@W21)) ----
__global__ __launch_bounds__(256) void gemm3_kernel(const float* __restrict__ x,
                                                    const float* __restrict__ W1,
                                                    const float* __restrict__ b1,
                                                    const float* __restrict__ W20,
                                                    const float* __restrict__ W21,
                                                    const float* __restrict__ b2,
                                                    const float* __restrict__ dis,
                                                    unsigned short* __restrict__ h16,
                                                    unsigned short* __restrict__ p16,
                                                    unsigned short* __restrict__ g16,
                                                    int n) {
    __shared__ __align__(16) float sA[64][68];
    __shared__ __align__(16) float sW1[64][64];
    __shared__ __align__(16) float sW20[64][64];
    __shared__ __align__(16) float sW21[64][64];
    int t = threadIdx.x;
    for (int i = t; i < 4096; i += 256) {
        sW1[i >> 6][i & 63] = W1[i];
        sW20[i >> 6][i & 63] = W20[i];
        sW21[i >> 6][i & 63] = W21[i];
    }
    int r0 = blockIdx.x * 64;
    {
        int rr0 = t >> 4, k0 = (t & 15) * 4;
        for (int rr = rr0; rr < 64; rr += 16) {
            int grow = r0 + rr;
            float4 v = make_float4(0.f, 0.f, 0.f, 0.f);
            if (grow < n) v = *(const float4*)&x[(size_t)grow * 64 + k0];
            sA[k0][rr] = v.x; sA[k0 + 1][rr] = v.y;
            sA[k0 + 2][rr] = v.z; sA[k0 + 3][rr] = v.w;
        }
    }
    __syncthreads();
    int tr = t >> 4, tc = t & 15;

    float acc[4][4] = {};
    for (int k = 0; k < 64; ++k) {
        float4 a = *(const float4*)&sA[k][tr * 4];
        float4 b = *(const float4*)&sW1[k][tc * 4];
        float av[4] = {a.x, a.y, a.z, a.w};
        float bv[4] = {b.x, b.y, b.z, b.w};
#pragma unroll
        for (int i = 0; i < 4; ++i)
#pragma unroll
            for (int j = 0; j < 4; ++j) acc[i][j] = fmaf(av[i], bv[j], acc[i][j]);
    }
    float4 bv1 = *(const float4*)&b1[tc * 4];
    float hv[4][4];
#pragma unroll
    for (int i = 0; i < 4; ++i) {
        hv[i][0] = fmaxf(acc[i][0] + bv1.x, 0.f);
        hv[i][1] = fmaxf(acc[i][1] + bv1.y, 0.f);
        hv[i][2] = fmaxf(acc[i][2] + bv1.z, 0.f);
        hv[i][3] = fmaxf(acc[i][3] + bv1.w, 0.f);
    }
#pragma unroll
    for (int i = 0; i < 4; ++i) {
        int grow = r0 + tr * 4 + i;
        if (grow < n) {
            ushort4 o;
            o.x = f2bf(hv[i][0]); o.y = f2bf(hv[i][1]);
            o.z = f2bf(hv[i][2]); o.w = f2bf(hv[i][3]);
            *(ushort4*)&h16[(size_t)grow * 64 + tc * 4] = o;
        }
    }
    __syncthreads();
#pragma unroll
    for (int i = 0; i < 4; ++i)
#pragma unroll
        for (int j = 0; j < 4; ++j) sA[tc * 4 + j][tr * 4 + i] = hv[i][j];
    __syncthreads();

    float accP[4][4] = {}, accG[4][4] = {};
    for (int k = 0; k < 64; ++k) {
        float4 a = *(const float4*)&sA[k][tr * 4];
        float4 bp = *(const float4*)&sW20[k][tc * 4];
        float4 bg = *(const float4*)&sW21[k][tc * 4];
        float av[4] = {a.x, a.y, a.z, a.w};
        float bpv[4] = {bp.x, bp.y, bp.z, bp.w};
        float bgv[4] = {bg.x, bg.y, bg.z, bg.w};
#pragma unroll
        for (int i = 0; i < 4; ++i)
#pragma unroll
            for (int j = 0; j < 4; ++j) {
                accP[i][j] = fmaf(av[i], bpv[j], accP[i][j]);
                accG[i][j] = fmaf(av[i], bgv[j], accG[i][j]);
            }
    }
    float4 bv2 = *(const float4*)&b2[tc * 4];
#pragma unroll
    for (int i = 0; i < 4; ++i) {
        int grow = r0 + tr * 4 + i;
        if (grow < n) {
            float dr = dis[grow];
            ushort4 op, og;
            op.x = f2bf(accP[i][0] + bv2.x); op.y = f2bf(accP[i][1] + bv2.y);
            op.z = f2bf(accP[i][2] + bv2.z); op.w = f2bf(accP[i][3] + bv2.w);
            og.x = f2bf(dr * accG[i][0]); og.y = f2bf(dr * accG[i][1]);
            og.z = f2bf(dr * accG[i][2]); og.w = f2bf(dr * accG[i][3]);
            *(ushort4*)&p16[(size_t)grow * 64 + tc * 4] = op;
            *(ushort4*)&g16[(size_t)grow * 64 + tc * 4] = og;
        }
    }
}

// ---- gather + epilogue: paired-feature gather (2 edges / VMEM inst) ----
__global__ __launch_bounds__(256, 8) void gather_out_kernel(
        const int* __restrict__ rowptr, const int* __restrict__ cntD,
        const int* __restrict__ csr, const float* __restrict__ dis,
        const uint32_t* __restrict__ gp, const uint32_t* __restrict__ pp,
        const uint32_t* __restrict__ hp, const float* __restrict__ Wl,
        const float* __restrict__ bl, float* __restrict__ out, int n) {
    __shared__ __align__(16) float so[4][68];     // h2 rows
    __shared__ __align__(16) float sWlT[10][68];  // Wl transposed
    __shared__ float sout[4][12];
    int t = threadIdx.x;
    if (t < 160) {
        float4 w = *(const float4*)&Wl[t * 4];
        int i0 = t * 4;
        sWlT[i0 % 10][i0 / 10] = w.x;
        sWlT[(i0 + 1) % 10][(i0 + 1) / 10] = w.y;
        sWlT[(i0 + 2) % 10][(i0 + 2) / 10] = w.z;
        sWlT[(i0 + 3) % 10][(i0 + 3) / 10] = w.w;
    }
    int p = t & 31;                 // feature-pair index (features 2p, 2p+1)
    int eslot = (t >> 5) & 1;       // which edge of the pair this lane serves
    int wid = __builtin_amdgcn_readfirstlane(t >> 6);
    int row = blockIdx.x * 4 + wid;
    if (row < n) {
        int m = cntD[row], rs = rowptr[row];
        float disd = dis[row];
        float l0 = 0.f, l1 = 0.f, l2 = 0.f, l3 = 0.f;
        float h0 = 0.f, h1 = 0.f, h2a = 0.f, h3 = 0.f;
        int k = 0;
        for (; k + 16 <= m; k += 16) {
            int sA0 = csr[rs + k + 0],  sA1 = csr[rs + k + 1];
            int sA2 = csr[rs + k + 2],  sA3 = csr[rs + k + 3];
            int sA4 = csr[rs + k + 4],  sA5 = csr[rs + k + 5];
            int sA6 = csr[rs + k + 6],  sA7 = csr[rs + k + 7];
            int sA8 = csr[rs + k + 8],  sA9 = csr[rs + k + 9];
            int sAa = csr[rs + k + 10], sAb = csr[rs + k + 11];
            int sAc = csr[rs + k + 12], sAd = csr[rs + k + 13];
            int sAe = csr[rs + k + 14], sAf = csr[rs + k + 15];
            int e0 = eslot ? sA1 : sA0;
            int e1 = eslot ? sA3 : sA2;
            int e2 = eslot ? sA5 : sA4;
            int e3 = eslot ? sA7 : sA6;
            int e4 = eslot ? sA9 : sA8;
            int e5 = eslot ? sAb : sAa;
            int e6 = eslot ? sAd : sAc;
            int e7 = eslot ? sAf : sAe;
            uint32_t u0 = gp[(size_t)e0 * 32 + p];
            uint32_t u1 = gp[(size_t)e1 * 32 + p];
            uint32_t u2 = gp[(size_t)e2 * 32 + p];
            uint32_t u3 = gp[(size_t)e3 * 32 + p];
            uint32_t u4 = gp[(size_t)e4 * 32 + p];
            uint32_t u5 = gp[(size_t)e5 * 32 + p];
            uint32_t u6 = gp[(size_t)e6 * 32 + p];
            uint32_t u7 = gp[(size_t)e7 * 32 + p];
            l0 += lo_of(u0); h0 += hi_of(u0);
            l1 += lo_of(u1); h1 += hi_of(u1);
            l2 += lo_of(u2); h2a += hi_of(u2);
            l3 += lo_of(u3); h3 += hi_of(u3);
            l0 += lo_of(u4); h0 += hi_of(u4);
            l1 += lo_of(u5); h1 += hi_of(u5);
            l2 += lo_of(u6); h2a += hi_of(u6);
            l3 += lo_of(u7); h3 += hi_of(u7);
        }
        for (; k + 2 <= m; k += 2) {
            int s0 = csr[rs + k], s1 = csr[rs + k + 1];
            int e = eslot ? s1 : s0;
            uint32_t u = gp[(size_t)e * 32 + p];
            l0 += lo_of(u); h0 += hi_of(u);
        }
        if (k < m) {
            int s0 = csr[rs + k];
            if (eslot == 0) {
                uint32_t u = gp[(size_t)s0 * 32 + p];
                l0 += lo_of(u); h0 += hi_of(u);
            }
        }
        float alo = (l0 + l1) + (l2 + l3);
        float ahi = (h0 + h1) + (h2a + h3);
        alo += __shfl_xor(alo, 32);
        ahi += __shfl_xor(ahi, 32);
        uint32_t up = pp[(size_t)row * 32 + p];
        uint32_t uh = hp[(size_t)row * 32 + p];
        float h2lo = fmaxf(lo_of(up) - disd * alo, 0.f) + lo_of(uh);
        float h2hi = fmaxf(hi_of(up) - disd * ahi, 0.f) + hi_of(uh);
        if (eslot == 0) {
            so[wid][2 * p] = h2lo;
            so[wid][2 * p + 1] = h2hi;
        }
    }
    __syncthreads();
    if (t < 40) {
        int r = t / 10, j = t % 10;
        float acc = bl[j];
#pragma unroll
        for (int k0 = 0; k0 < 64; k0 += 4) {
            float4 a = *(const float4*)&so[r][k0];
            float4 b = *(const float4*)&sWlT[j][k0];
            acc = fmaf(a.x, b.x, acc);
            acc = fmaf(a.y, b.y, acc);
            acc = fmaf(a.z, b.z, acc);
            acc = fmaf(a.w, b.w, acc);
        }
        sout[r][j] = acc;
    }
    __syncthreads();
    if (t < 64) {
        int r = t >> 4, l16 = t & 15;
        float v = (l16 < 10) ? sout[r][l16] : -1e30f;
        float mm = v;
#pragma unroll
        for (int d = 1; d < 16; d <<= 1) mm = fmaxf(mm, __shfl_xor(mm, d, 16));
        float e = (l16 < 10) ? expf(v - mm) : 0.f;
        float ss = e;
#pragma unroll
        for (int d = 1; d < 16; d <<= 1) ss += __shfl_xor(ss, d, 16);
        int grow = blockIdx.x * 4 + r;
        if (grow < n && l16 < 10)
            out[(size_t)grow * 10 + l16] = v - mm - logf(ss);
    }
}

extern "C" void kernel_launch(void* const* d_in, const int* in_sizes, int n_in,
                              void* d_out, int out_size, void* d_ws, size_t ws_size,
                              hipStream_t stream) {
    const float* x   = (const float*)d_in[0];
    const int*   ei  = (const int*)d_in[1];
    const float* W1  = (const float*)d_in[2];
    const float* b1  = (const float*)d_in[3];
    const float* W20 = (const float*)d_in[4];
    const float* W21 = (const float*)d_in[5];
    const float* b2  = (const float*)d_in[6];
    const float* Wl  = (const float*)d_in[7];
    const float* bl  = (const float*)d_in[8];
    float* out = (float*)d_out;

    int n = in_sizes[0] / 64;   // 50000
    int E = in_sizes[1] / 2;    // 800000

    char* ws = (char*)d_ws;
    size_t off = 0;
    auto alloc = [&](size_t bytes) {
        void* p = ws + off;
        off = (off + bytes + 255) & ~(size_t)255;
        return p;
    };
    int*       gcur   = (int*)alloc((size_t)NBKT * 4);
    uint32_t*  pairs  = (uint32_t*)alloc((size_t)NBKT * BCAP * 4);  // 5.2 MB
    int*       csr    = (int*)alloc((size_t)NBKT * BCAP * 4);       // 5.2 MB
    int*       rowptr = (int*)alloc((size_t)n * 4);
    int*       cntD   = (int*)alloc((size_t)n * 4);
    int*       degS   = (int*)alloc((size_t)n * 4);
    float*     dis    = (float*)alloc((size_t)n * 4);
    unsigned short* h16 = (unsigned short*)alloc((size_t)n * 64 * 2);
    unsigned short* p16 = (unsigned short*)alloc((size_t)n * 64 * 2);
    unsigned short* g16 = (unsigned short*)alloc((size_t)n * 64 * 2);

    hipMemsetAsync(gcur, 0, (size_t)NBKT * 4, stream);
    hipMemsetAsync(degS, 0, (size_t)n * 4, stream);

    int nchunk = (E + CHUNK - 1) / CHUNK;
    binA_kernel<<<nchunk, 256, 0, stream>>>(ei, gcur, pairs, E);
    deghist_kernel<<<4 * NSLICE, 256, 0, stream>>>(ei, degS, E, n);
    binB_kernel<<<NBKT, 256, 0, stream>>>(gcur, pairs, csr, rowptr, cntD, degS, dis, n);
    gemm3_kernel<<<(n + 63) / 64, 256, 0, stream>>>(x, W1, b1, W20, W21, b2, dis,
                                                    h16, p16, g16, n);
    gather_out_kernel<<<(n + 3) / 4, 256, 0, stream>>>(rowptr, cntD, csr, dis,
                                                       (const uint32_t*)g16,
                                                       (const uint32_t*)p16,
                                                       (const uint32_t*)h16,
                                                       Wl, bl, out, n);
}

// Round 14
// 175.917 us; speedup vs baseline: 1.1286x; 1.0662x over previous
//
#include <hip/hip_runtime.h>
#include <math.h>
#include <stdint.h>

// ChebConv GNN: N=50000, E=800000, F=H=64, C=10.
//   degS[i] = out-degree of i ; dis = rsqrt(degS) (0 if 0)
//   h  = relu(x @ W1 + b1)                       (stored bf16)
//   p0 = h @ W20 + b2                            (stored bf16)
//   g' = bf16( dis[row] * (h @ W21) )
//   lap[dst] = -dis[dst] * sum_{src in N(dst)} g'[src]    (CSR gather)
//   out = log_softmax( (relu(p0 + lap) + h) @ Wl + bl )
//
// gemm3 now uses mfma_f32_16x16x32_bf16 (2 MFMA per 16x16 output tile, K=64).
// LDS tiles XOR-swizzled (byte ^= (row&7)<<4) to avoid 16-way bank conflict
// on stride-128B ds_read_b128 (guide §6 G4).

#define NBKT 256
#define BCAP 5120
#define CHUNK 2048
#define RB 12800
#define NSLICE 64

typedef __attribute__((ext_vector_type(8))) short bf16x8;
typedef __attribute__((ext_vector_type(4))) float f32x4;

__device__ __forceinline__ unsigned short f2bf(float f) {
    uint32_t u; __builtin_memcpy(&u, &f, 4);
    u += 0x7fffu + ((u >> 16) & 1u);          // RNE
    return (unsigned short)(u >> 16);
}
__device__ __forceinline__ float bf2f(unsigned short s) {
    uint32_t u = (uint32_t)s << 16; float f; __builtin_memcpy(&f, &u, 4);
    return f;
}
__device__ __forceinline__ float lo_of(uint32_t u) {
    uint32_t v = u << 16; float f; __builtin_memcpy(&f, &v, 4); return f;
}
__device__ __forceinline__ float hi_of(uint32_t u) {
    uint32_t v = u & 0xffff0000u; float f; __builtin_memcpy(&f, &v, 4); return f;
}

// ---------------- Phase A: coarse binning by dst>>8 ----------------
__global__ __launch_bounds__(256) void binA_kernel(const int* __restrict__ ei,
                                                   int* __restrict__ gcur,
                                                   uint32_t* __restrict__ pairs,
                                                   int E) {
    __shared__ uint32_t stage[CHUNK];
    __shared__ int cnt[NBKT], obase[NBKT], goff[NBKT], curs[NBKT];
    __shared__ int wpart[4], stot;
    int t = threadIdx.x, lane = t & 63, wv = t >> 6;
    int e0 = blockIdx.x * CHUNK;
    int s[8], d[8];
    bool val[8];
#pragma unroll
    for (int j = 0; j < 8; ++j) {
        int e = e0 + j * 256 + t;
        val[j] = e < E;
        s[j] = val[j] ? ei[e] : 0;
        d[j] = val[j] ? ei[E + e] : 0;
    }
    cnt[t] = 0;
    __syncthreads();
#pragma unroll
    for (int j = 0; j < 8; ++j)
        if (val[j]) atomicAdd(&cnt[d[j] >> 8], 1);
    __syncthreads();
    int cv = cnt[t];
    int v = cv;
#pragma unroll
    for (int dd = 1; dd < 64; dd <<= 1) {
        int u = __shfl_up(v, dd);
        if (lane >= dd) v += u;
    }
    if (lane == 63) wpart[wv] = v;
    __syncthreads();
    if (t == 0) {
        int r = 0;
#pragma unroll
        for (int w = 0; w < 4; ++w) { int tmp = wpart[w]; wpart[w] = r; r += tmp; }
        stot = r;
    }
    __syncthreads();
    int eb = wpart[wv] + v - cv;
    obase[t] = eb;
    curs[t] = eb;
    goff[t] = (cv > 0) ? atomicAdd(&gcur[t], cv) : 0;
    __syncthreads();
#pragma unroll
    for (int j = 0; j < 8; ++j)
        if (val[j]) {
            int b = d[j] >> 8;
            int pos = atomicAdd(&curs[b], 1);
            stage[pos] = ((uint32_t)d[j] << 16) | (uint32_t)s[j];  // b:8|ld:8|src:16
        }
    __syncthreads();
    int tot = stot;
    for (int k = t; k < tot; k += 256) {
        uint32_t u = stage[k];
        int b = (int)(u >> 24);
        int slot = goff[b] + (k - obase[b]);
        if (slot < BCAP) pairs[(size_t)b * BCAP + slot] = u;
    }
}

// ------- degree histogram: 4 ranges x 64 slices, coalesced merge atomics -------
__global__ __launch_bounds__(256) void deghist_kernel(const int* __restrict__ ei,
                                                      int* __restrict__ degS,
                                                      int E, int n) {
    __shared__ int bins[RB];
    int t = threadIdx.x;
    int r = blockIdx.x & 3;
    int sl = blockIdx.x >> 2;
    int lo = r * RB;
    for (int i = t; i < RB; i += 256) bins[i] = 0;
    __syncthreads();
    int per = (E + NSLICE - 1) / NSLICE;
    int b0 = sl * per, b1 = b0 + per; if (b1 > E) b1 = E;
    for (int e = b0 + t; e < b1; e += 256) {
        int s = ei[e] - lo;
        if ((unsigned)s < (unsigned)RB) atomicAdd(&bins[s], 1);
    }
    __syncthreads();
    int hi = n - lo; if (hi > RB) hi = RB;
    for (int i = t; i < hi; i += 256) {
        int v = bins[i];
        if (v) atomicAdd(&degS[lo + i], v);
    }
}

// ------- Phase B: per-bucket CSR build (+ folded dis = rsqrt(degS)) -------
__global__ __launch_bounds__(256) void binB_kernel(const int* __restrict__ gcur,
                                                   const uint32_t* __restrict__ pairs,
                                                   int* __restrict__ csr,
                                                   int* __restrict__ rowptr,
                                                   int* __restrict__ cntD,
                                                   const int* __restrict__ degS,
                                                   float* __restrict__ dis, int n) {
    __shared__ int hist[NBKT], obase[NBKT], curs[NBKT];
    __shared__ int wpart[4];
    int t = threadIdx.x, lane = t & 63, wv = t >> 6;
    int b = blockIdx.x;
    {
        int node = b * 256 + t;
        if (node < n) {
            int dsum = degS[node];
            dis[node] = (dsum > 0) ? rsqrtf((float)dsum) : 0.0f;
        }
    }
    int nb = gcur[b]; if (nb > BCAP) nb = BCAP;
    hist[t] = 0;
    __syncthreads();
    const uint32_t* bp = pairs + (size_t)b * BCAP;
    for (int k = t; k < nb; k += 256) {
        int ld = (int)((bp[k] >> 16) & 255);
        atomicAdd(&hist[ld], 1);
    }
    __syncthreads();
    int cv = hist[t];
    int v = cv;
#pragma unroll
    for (int dd = 1; dd < 64; dd <<= 1) {
        int u = __shfl_up(v, dd);
        if (lane >= dd) v += u;
    }
    if (lane == 63) wpart[wv] = v;
    __syncthreads();
    if (t == 0) {
        int r = 0;
#pragma unroll
        for (int w = 0; w < 4; ++w) { int tmp = wpart[w]; wpart[w] = r; r += tmp; }
    }
    __syncthreads();
    int eb = wpart[wv] + v - cv;
    obase[t] = eb;
    curs[t] = eb;
    int node = b * 256 + t;
    if (node < n) {
        rowptr[node] = b * BCAP + eb;
        cntD[node] = cv;
    }
    __syncthreads();
    for (int k = t; k < nb; k += 256) {
        uint32_t u = bp[k];
        int ld = (int)((u >> 16) & 255);
        int pos = atomicAdd(&curs[ld], 1);
        csr[(size_t)b * BCAP + pos] = (int)(u & 0xffffu);
    }
}

// ---- MFMA triple GEMM: h16=relu(x@W1+b1); p16=h@W20+b2; g16=bf16(dis*(h@W21))
// 64 rows/block, 4 waves; wave w owns row stripe [16w,16w+16).
// A: lane reads T[row=l&15][k=(l>>4)*8+j]; B from WT[out][k] (same pattern).
// C: col=l&15, row=(l>>4)*4+reg (m89-verified).
__global__ __launch_bounds__(256) void gemm3_kernel(const float* __restrict__ x,
                                                    const float* __restrict__ W1,
                                                    const float* __restrict__ b1,
                                                    const float* __restrict__ W20,
                                                    const float* __restrict__ W21,
                                                    const float* __restrict__ b2,
                                                    const float* __restrict__ dis,
                                                    unsigned short* __restrict__ h16,
                                                    unsigned short* __restrict__ p16,
                                                    unsigned short* __restrict__ g16,
                                                    int n) {
    __shared__ __align__(16) unsigned short sA[64 * 64];     // x tile, then h tile
    __shared__ __align__(16) unsigned short sW1T[64 * 64];   // W1^T [out][k]
    __shared__ __align__(16) unsigned short sW2T[128 * 64];  // [W20|W21]^T
    __shared__ float sDis[64], sB1[64], sB2[64];
    int t = threadIdx.x;
    int r0 = blockIdx.x * 64;
    if (t < 64) {
        sB1[t] = b1[t];
        sB2[t] = b2[t];
        int grow = r0 + t;
        sDis[t] = (grow < n) ? dis[grow] : 0.f;
    }
    // stage weights transposed + bf16 (swizzled scalar writes)
    for (int idx = t; idx < 4096; idx += 256) {
        int k = idx >> 6, o = idx & 63;
        int byte = (o * 128 + k * 2) ^ ((o & 7) << 4);
        *(unsigned short*)((char*)sW1T + byte) = f2bf(W1[idx]);
        *(unsigned short*)((char*)sW2T + byte) = f2bf(W20[idx]);
        int byte2 = ((o + 64) * 128 + k * 2) ^ ((o & 7) << 4);
        *(unsigned short*)((char*)sW2T + byte2) = f2bf(W21[idx]);
    }
    // stage x tile as bf16, swizzled
    {
        int rr = t >> 4, k0 = (t & 15) * 4;
        for (int r = rr; r < 64; r += 16) {
            int grow = r0 + r;
            float4 v = make_float4(0.f, 0.f, 0.f, 0.f);
            if (grow < n) v = *(const float4*)&x[(size_t)grow * 64 + k0];
            ushort4 u;
            u.x = f2bf(v.x); u.y = f2bf(v.y); u.z = f2bf(v.z); u.w = f2bf(v.w);
            int byte = (r * 128 + k0 * 2) ^ ((r & 7) << 4);
            *(ushort4*)((char*)sA + byte) = u;
        }
    }
    __syncthreads();
    int w = t >> 6, l = t & 63;
    int lr = l & 15, kg = l >> 4;

    // ---- phase 1: h stripe ----
    bf16x8 a0, a1;
    {
        int row = 16 * w + lr;
        int sw = (row & 7) << 4;
        a0 = *(bf16x8*)((char*)sA + ((row * 128 + kg * 16) ^ sw));
        a1 = *(bf16x8*)((char*)sA + ((row * 128 + 64 + kg * 16) ^ sw));
    }
    float hreg[4][4];
#pragma unroll
    for (int ct = 0; ct < 4; ++ct) {
        int orow = ct * 16 + lr;
        int sw = (orow & 7) << 4;
        bf16x8 bb0 = *(bf16x8*)((char*)sW1T + ((orow * 128 + kg * 16) ^ sw));
        bf16x8 bb1 = *(bf16x8*)((char*)sW1T + ((orow * 128 + 64 + kg * 16) ^ sw));
        f32x4 acc = {0.f, 0.f, 0.f, 0.f};
        acc = __builtin_amdgcn_mfma_f32_16x16x32_bf16(a0, bb0, acc, 0, 0, 0);
        acc = __builtin_amdgcn_mfma_f32_16x16x32_bf16(a1, bb1, acc, 0, 0, 0);
        float bias = sB1[ct * 16 + lr];
#pragma unroll
        for (int j = 0; j < 4; ++j) hreg[ct][j] = fmaxf(acc[j] + bias, 0.f);
    }
    // write h to global
#pragma unroll
    for (int ct = 0; ct < 4; ++ct)
#pragma unroll
        for (int j = 0; j < 4; ++j) {
            int grow = r0 + 16 * w + kg * 4 + j;
            if (grow < n) h16[(size_t)grow * 64 + ct * 16 + lr] = f2bf(hreg[ct][j]);
        }
    __syncthreads();   // all x reads done
    // repack h into sA (swizzled)
#pragma unroll
    for (int ct = 0; ct < 4; ++ct)
#pragma unroll
        for (int j = 0; j < 4; ++j) {
            int row = 16 * w + kg * 4 + j;
            int col = ct * 16 + lr;
            int byte = (row * 128 + col * 2) ^ ((row & 7) << 4);
            *(unsigned short*)((char*)sA + byte) = f2bf(hreg[ct][j]);
        }
    __syncthreads();

    // ---- phase 2: [p0|g] = h @ [W20|W21] ----
    {
        int row = 16 * w + lr;
        int sw = (row & 7) << 4;
        a0 = *(bf16x8*)((char*)sA + ((row * 128 + kg * 16) ^ sw));
        a1 = *(bf16x8*)((char*)sA + ((row * 128 + 64 + kg * 16) ^ sw));
    }
#pragma unroll
    for (int ct = 0; ct < 8; ++ct) {
        int orow = ct * 16 + lr;
        int sw = (orow & 7) << 4;
        bf16x8 bb0 = *(bf16x8*)((char*)sW2T + ((orow * 128 + kg * 16) ^ sw));
        bf16x8 bb1 = *(bf16x8*)((char*)sW2T + ((orow * 128 + 64 + kg * 16) ^ sw));
        f32x4 acc = {0.f, 0.f, 0.f, 0.f};
        acc = __builtin_amdgcn_mfma_f32_16x16x32_bf16(a0, bb0, acc, 0, 0, 0);
        acc = __builtin_amdgcn_mfma_f32_16x16x32_bf16(a1, bb1, acc, 0, 0, 0);
#pragma unroll
        for (int j = 0; j < 4; ++j) {
            int row = 16 * w + kg * 4 + j;
            int grow = r0 + row;
            if (grow >= n) continue;
            if (ct < 4) {
                int col = ct * 16 + lr;
                p16[(size_t)grow * 64 + col] = f2bf(acc[j] + sB2[col]);
            } else {
                int col = (ct - 4) * 16 + lr;
                g16[(size_t)grow * 64 + col] = f2bf(sDis[row] * acc[j]);
            }
        }
    }
}

// ---- gather + epilogue: paired-feature gather (2 edges / VMEM inst) ----
__global__ __launch_bounds__(256, 8) void gather_out_kernel(
        const int* __restrict__ rowptr, const int* __restrict__ cntD,
        const int* __restrict__ csr, const float* __restrict__ dis,
        const uint32_t* __restrict__ gp, const uint32_t* __restrict__ pp,
        const uint32_t* __restrict__ hp, const float* __restrict__ Wl,
        const float* __restrict__ bl, float* __restrict__ out, int n) {
    __shared__ __align__(16) float so[4][68];
    __shared__ __align__(16) float sWlT[10][68];
    __shared__ float sout[4][12];
    int t = threadIdx.x;
    if (t < 160) {
        float4 w = *(const float4*)&Wl[t * 4];
        int i0 = t * 4;
        sWlT[i0 % 10][i0 / 10] = w.x;
        sWlT[(i0 + 1) % 10][(i0 + 1) / 10] = w.y;
        sWlT[(i0 + 2) % 10][(i0 + 2) / 10] = w.z;
        sWlT[(i0 + 3) % 10][(i0 + 3) / 10] = w.w;
    }
    int p = t & 31;
    int eslot = (t >> 5) & 1;
    int wid = __builtin_amdgcn_readfirstlane(t >> 6);
    int row = blockIdx.x * 4 + wid;
    if (row < n) {
        int m = cntD[row], rs = rowptr[row];
        float disd = dis[row];
        float l0 = 0.f, l1 = 0.f, l2 = 0.f, l3 = 0.f;
        float h0 = 0.f, h1 = 0.f, h2a = 0.f, h3 = 0.f;
        int k = 0;
        for (; k + 16 <= m; k += 16) {
            int sA0 = csr[rs + k + 0],  sA1 = csr[rs + k + 1];
            int sA2 = csr[rs + k + 2],  sA3 = csr[rs + k + 3];
            int sA4 = csr[rs + k + 4],  sA5 = csr[rs + k + 5];
            int sA6 = csr[rs + k + 6],  sA7 = csr[rs + k + 7];
            int sA8 = csr[rs + k + 8],  sA9 = csr[rs + k + 9];
            int sAa = csr[rs + k + 10], sAb = csr[rs + k + 11];
            int sAc = csr[rs + k + 12], sAd = csr[rs + k + 13];
            int sAe = csr[rs + k + 14], sAf = csr[rs + k + 15];
            int e0 = eslot ? sA1 : sA0;
            int e1 = eslot ? sA3 : sA2;
            int e2 = eslot ? sA5 : sA4;
            int e3 = eslot ? sA7 : sA6;
            int e4 = eslot ? sA9 : sA8;
            int e5 = eslot ? sAb : sAa;
            int e6 = eslot ? sAd : sAc;
            int e7 = eslot ? sAf : sAe;
            uint32_t u0 = gp[(size_t)e0 * 32 + p];
            uint32_t u1 = gp[(size_t)e1 * 32 + p];
            uint32_t u2 = gp[(size_t)e2 * 32 + p];
            uint32_t u3 = gp[(size_t)e3 * 32 + p];
            uint32_t u4 = gp[(size_t)e4 * 32 + p];
            uint32_t u5 = gp[(size_t)e5 * 32 + p];
            uint32_t u6 = gp[(size_t)e6 * 32 + p];
            uint32_t u7 = gp[(size_t)e7 * 32 + p];
            l0 += lo_of(u0); h0 += hi_of(u0);
            l1 += lo_of(u1); h1 += hi_of(u1);
            l2 += lo_of(u2); h2a += hi_of(u2);
            l3 += lo_of(u3); h3 += hi_of(u3);
            l0 += lo_of(u4); h0 += hi_of(u4);
            l1 += lo_of(u5); h1 += hi_of(u5);
            l2 += lo_of(u6); h2a += hi_of(u6);
            l3 += lo_of(u7); h3 += hi_of(u7);
        }
        for (; k + 2 <= m; k += 2) {
            int s0 = csr[rs + k], s1 = csr[rs + k + 1];
            int e = eslot ? s1 : s0;
            uint32_t u = gp[(size_t)e * 32 + p];
            l0 += lo_of(u); h0 += hi_of(u);
        }
        if (k < m) {
            int s0 = csr[rs + k];
            if (eslot == 0) {
                uint32_t u = gp[(size_t)s0 * 32 + p];
                l0 += lo_of(u); h0 += hi_of(u);
            }
        }
        float alo = (l0 + l1) + (l2 + l3);
        float ahi = (h0 + h1) + (h2a + h3);
        alo += __shfl_xor(alo, 32);
        ahi += __shfl_xor(ahi, 32);
        uint32_t up = pp[(size_t)row * 32 + p];
        uint32_t uh = hp[(size_t)row * 32 + p];
        float h2lo = fmaxf(lo_of(up) - disd * alo, 0.f) + lo_of(uh);
        float h2hi = fmaxf(hi_of(up) - disd * ahi, 0.f) + hi_of(uh);
        if (eslot == 0) {
            so[wid][2 * p] = h2lo;
            so[wid][2 * p + 1] = h2hi;
        }
    }
    __syncthreads();
    if (t < 40) {
        int r = t / 10, j = t % 10;
        float acc = bl[j];
#pragma unroll
        for (int k0 = 0; k0 < 64; k0 += 4) {
            float4 a = *(const float4*)&so[r][k0];
            float4 b = *(const float4*)&sWlT[j][k0];
            acc = fmaf(a.x, b.x, acc);
            acc = fmaf(a.y, b.y, acc);
            acc = fmaf(a.z, b.z, acc);
            acc = fmaf(a.w, b.w, acc);
        }
        sout[r][j] = acc;
    }
    __syncthreads();
    if (t < 64) {
        int r = t >> 4, l16 = t & 15;
        float v = (l16 < 10) ? sout[r][l16] : -1e30f;
        float mm = v;
#pragma unroll
        for (int d = 1; d < 16; d <<= 1) mm = fmaxf(mm, __shfl_xor(mm, d, 16));
        float e = (l16 < 10) ? expf(v - mm) : 0.f;
        float ss = e;
#pragma unroll
        for (int d = 1; d < 16; d <<= 1) ss += __shfl_xor(ss, d, 16);
        int grow = blockIdx.x * 4 + r;
        if (grow < n && l16 < 10)
            out[(size_t)grow * 10 + l16] = v - mm - logf(ss);
    }
}

extern "C" void kernel_launch(void* const* d_in, const int* in_sizes, int n_in,
                              void* d_out, int out_size, void* d_ws, size_t ws_size,
                              hipStream_t stream) {
    const float* x   = (const float*)d_in[0];
    const int*   ei  = (const int*)d_in[1];
    const float* W1  = (const float*)d_in[2];
    const float* b1  = (const float*)d_in[3];
    const float* W20 = (const float*)d_in[4];
    const float* W21 = (const float*)d_in[5];
    const float* b2  = (const float*)d_in[6];
    const float* Wl  = (const float*)d_in[7];
    const float* bl  = (const float*)d_in[8];
    float* out = (float*)d_out;

    int n = in_sizes[0] / 64;   // 50000
    int E = in_sizes[1] / 2;    // 800000

    char* ws = (char*)d_ws;
    size_t off = 0;
    auto alloc = [&](size_t bytes) {
        void* p = ws + off;
        off = (off + bytes + 255) & ~(size_t)255;
        return p;
    };
    int*       gcur   = (int*)alloc((size_t)NBKT * 4);
    uint32_t*  pairs  = (uint32_t*)alloc((size_t)NBKT * BCAP * 4);  // 5.2 MB
    int*       csr    = (int*)alloc((size_t)NBKT * BCAP * 4);       // 5.2 MB
    int*       rowptr = (int*)alloc((size_t)n * 4);
    int*       cntD   = (int*)alloc((size_t)n * 4);
    int*       degS   = (int*)alloc((size_t)n * 4);
    float*     dis    = (float*)alloc((size_t)n * 4);
    unsigned short* h16 = (unsigned short*)alloc((size_t)n * 64 * 2);
    unsigned short* p16 = (unsigned short*)alloc((size_t)n * 64 * 2);
    unsigned short* g16 = (unsigned short*)alloc((size_t)n * 64 * 2);

    hipMemsetAsync(gcur, 0, (size_t)NBKT * 4, stream);
    hipMemsetAsync(degS, 0, (size_t)n * 4, stream);

    int nchunk = (E + CHUNK - 1) / CHUNK;
    binA_kernel<<<nchunk, 256, 0, stream>>>(ei, gcur, pairs, E);
    deghist_kernel<<<4 * NSLICE, 256, 0, stream>>>(ei, degS, E, n);
    binB_kernel<<<NBKT, 256, 0, stream>>>(gcur, pairs, csr, rowptr, cntD, degS, dis, n);
    gemm3_kernel<<<(n + 63) / 64, 256, 0, stream>>>(x, W1, b1, W20, W21, b2, dis,
                                                    h16, p16, g16, n);
    gather_out_kernel<<<(n + 3) / 4, 256, 0, stream>>>(rowptr, cntD, csr, dis,
                                                       (const uint32_t*)g16,
                                                       (const uint32_t*)p16,
                                                       (const uint32_t*)h16,
                                                       Wl, bl, out, n);
}